// Round 8
// baseline (1425.809 us; speedup 1.0000x reference)
//
#include <hip/hip_runtime.h>
#include <stdint.h>
#include <math.h>

#define NTOK 2048
#define HDIM 2048
#define FDIM 1024
#define NEXP 32
#define TOPK 4
#define NGRP 4
#define CAP  512

typedef _Float16 f16;
typedef _Float16 half8 __attribute__((ext_vector_type(8)));
typedef float f32x4 __attribute__((ext_vector_type(4)));

__device__ __forceinline__ int swz3(int n) { return (n ^ (n >> 2)) & 3; }

// ---------------- convert x fp32 [2048][2048] -> xbt fp16 k-chunked [64][2048][32] ----------------
__global__ __launch_bounds__(256) void convert_kernel(const float* __restrict__ x,
                                                      f16* __restrict__ xbt) {
  int i = blockIdx.x * 256 + threadIdx.x;
  int r = i >> 8;
  int c8 = (i & 255) << 3;
  const float* p = x + (size_t)r * HDIM + c8;
  f32x4 a = *(const f32x4*)p;
  f32x4 b = *(const f32x4*)(p + 4);
  half8 v;
  v[0] = (f16)a[0]; v[1] = (f16)a[1]; v[2] = (f16)a[2]; v[3] = (f16)a[3];
  v[4] = (f16)b[0]; v[5] = (f16)b[1]; v[6] = (f16)b[2]; v[7] = (f16)b[3];
  int t = c8 >> 5;
  *(half8*)((char*)xbt + (size_t)t * 131072 + r * 64 + (c8 & 31) * 2) = v;
}

// ---------------- gate ----------------
__global__ __launch_bounds__(256) void gate_kernel(const float* __restrict__ x,
                                                   const float* __restrict__ gw,
                                                   const float* __restrict__ gb,
                                                   int* __restrict__ tidx,
                                                   float* __restrict__ tw) {
  int t = blockIdx.x;
  int tid = threadIdx.x;
  int e = tid >> 3, p = tid & 7;
  const f32x4* xr = (const f32x4*)(x + (size_t)t * HDIM);
  const f32x4* wr = (const f32x4*)(gw + (size_t)e * HDIM);
  float s = 0.f;
  for (int c = 0; c < 64; c++) {
    f32x4 a = xr[p + c * 8], w = wr[p + c * 8];
    s += a[0] * w[0] + a[1] * w[1] + a[2] * w[2] + a[3] * w[3];
  }
  s += __shfl_down(s, 4, 8);
  s += __shfl_down(s, 2, 8);
  s += __shfl_down(s, 1, 8);
  __shared__ float lg[NEXP];
  if (p == 0) lg[e] = s;
  __syncthreads();
  if (tid == 0) {
    float sc[NEXP], scb[NEXP];
    for (int i = 0; i < NEXP; i++) {
      sc[i] = 1.f / (1.f + expf(-lg[i]));
      scb[i] = sc[i] + gb[i];
    }
    float gs[NGRP];
    for (int g = 0; g < NGRP; g++) {
      float m1 = -1e30f, m2 = -1e30f;
      for (int j = 0; j < 8; j++) {
        float v = scb[g * 8 + j];
        if (v > m1) { m2 = m1; m1 = v; }
        else if (v > m2) m2 = v;
      }
      gs[g] = m1 + m2;
    }
    int g1 = 0; float bv = gs[0];
    for (int g = 1; g < NGRP; g++) if (gs[g] > bv) { bv = gs[g]; g1 = g; }
    int g2 = -1; bv = -1e30f;
    for (int g = 0; g < NGRP; g++) if (g != g1 && gs[g] > bv) { bv = gs[g]; g2 = g; }
    float cand[NEXP];
    for (int i = 0; i < NEXP; i++) {
      int g = i >> 3;
      cand[i] = (g == g1 || g == g2) ? scb[i] : 0.0f;
    }
    int isel[TOPK]; float wsel[TOPK]; float wsum = 0.f;
    bool used[NEXP] = {};
    for (int k = 0; k < TOPK; k++) {
      int best = 0; float bw = -1e30f;
      for (int i = 0; i < NEXP; i++)
        if (!used[i] && cand[i] > bw) { bw = cand[i]; best = i; }
      used[best] = true;
      isel[k] = best;
      wsel[k] = sc[best];
      wsum += wsel[k];
    }
    float inv = 2.0f / (wsum + 1e-20f);
    for (int k = 0; k < TOPK; k++) {
      tidx[t * TOPK + k] = isel[k];
      tw[t * TOPK + k] = wsel[k] * inv;
    }
  }
}

// ---------------- dispatch ----------------
__global__ __launch_bounds__(256) void dispatch_kernel(const int* __restrict__ tidx,
                                                       const float* __restrict__ tw,
                                                       int* __restrict__ tok,
                                                       float* __restrict__ wt,
                                                       int* __restrict__ cnt) {
  int e = blockIdx.x, tid = threadIdx.x, wv = tid >> 6, lane = tid & 63;
  __shared__ int wsum[4];
  __shared__ int sbase;
  if (tid == 0) sbase = 0;
  __syncthreads();
  for (int c = 0; c < (NTOK * TOPK) / 256; c++) {
    int i = c * 256 + tid;
    int fe = tidx[i];
    bool flag = (fe == e);
    unsigned long long b = __ballot(flag ? 1 : 0);
    int lr = __popcll(b & ((1ull << lane) - 1ull));
    if (lane == 0) wsum[wv] = __popcll(b);
    __syncthreads();
    int off = 0;
    for (int w2 = 0; w2 < wv; w2++) off += wsum[w2];
    int tot = wsum[0] + wsum[1] + wsum[2] + wsum[3];
    int base = sbase;
    if (flag) {
      int pos = base + off + lr;
      if (pos < CAP) {
        tok[e * CAP + pos] = i >> 2;
        wt[e * CAP + pos] = tw[i];
      }
    }
    __syncthreads();
    if (tid == 0) sbase = base + tot;
  }
  __syncthreads();
  if (tid == 0) cnt[e] = min(sbase, CAP);
}

// ---------------- gather: xg[e][t][slot][32k] = xbt[t][tok[e][slot]], zero-padded ----------------
__global__ __launch_bounds__(256) void gather_kernel(const f16* __restrict__ xbt,
                                                     const int* __restrict__ tok,
                                                     const int* __restrict__ cnt,
                                                     f16* __restrict__ xg) {
  int bid = blockIdx.x;
  int t = bid & 63, e = bid >> 6;
  int cn = cnt[e];
  int tid = threadIdx.x;
  char* dst = (char*)xg + (size_t)e * 2097152 + (size_t)t * 32768;
  const char* srcb = (const char*)xbt + (size_t)t * 131072;
  for (int s = tid; s < CAP; s += 256) {
    uint4 v0 = {0,0,0,0}, v1 = {0,0,0,0}, v2 = {0,0,0,0}, v3 = {0,0,0,0};
    if (s < cn) {
      const uint4* sp = (const uint4*)(srcb + (size_t)tok[e * CAP + s] * 64);
      v0 = sp[0]; v1 = sp[1]; v2 = sp[2]; v3 = sp[3];
    }
    uint4* dp = (uint4*)(dst + s * 64);
    dp[0] = v0; dp[1] = v1; dp[2] = v2; dp[3] = v3;
  }
}

// ---------------- 1-wave barrier-free MFMA GEMM ----------------
// 64-thread blocks; each wave owns a row-stripe x col-tile, with its own
// private LDS B-buffer (write->read same wave: no s_barrier anywhere).
// B prefetched 2 tiles ahead in named reg sets E/O; A frags global->VGPR
// from k-chunked fp16 (L2-hot). Two "mats" always: MODE0/1 = w1/w3 (or
// sg/su); MODE2/3 = two 32-col halves of the single weight.
// MODE 0: routed up   -> hbuf k-chunked fp16 (silu(g)*u)
// MODE 1: shared up   -> hs k-chunked fp16
// MODE 2: routed down -> atomicAdd into out
// MODE 3: shared down -> plain store into out
template<int MODE>
__global__ __launch_bounds__(64, (MODE == 0 || MODE == 2) ? 2 : 3)
void gemm_kernel(const f16* __restrict__ Ag, const float* __restrict__ B0g,
                 const float* __restrict__ B1g, void* __restrict__ outp,
                 const int* __restrict__ tokL, const float* __restrict__ wtL,
                 const int* __restrict__ cntP) {
  constexpr bool DUALP = (MODE <= 1);
  constexpr bool ROUTED = (MODE == 0 || MODE == 2);
  constexpr int MF = ROUTED ? 8 : 4;          // 128 or 64 rows per wave
  constexpr int KD = (MODE == 2) ? 1024 : 2048;
  constexpr int NK = KD / 32;
  constexpr int ND = (MODE == 0) ? 1024 : 2048;   // B row length (floats)
  constexpr size_t TS = ROUTED ? 32768 : 131072;  // A k-chunk byte stride

  int G = gridDim.x;
  int bid = blockIdx.x;
  int t = (bid & 7) * (G >> 3) + (bid >> 3);   // XCD-chunked tile order

  int e = 0, rw, n;
  if constexpr (ROUTED) { rw = t & 3; n = (t >> 2) & 31; e = t >> 7; }
  else                  { rw = t & 31; n = t >> 5; }
  int n0 = n * (DUALP ? 32 : 64);
  int row0 = rw * (MF * 16);

  const char* Ab = (const char*)Ag;
  const float* B0 = B0g;
  const float* B1 = B1g;
  int Mcur = NTOK;
  if constexpr (ROUTED) {
    Mcur = cntP[e];
    int Mpad = (Mcur + 127) & ~127;
    if (row0 >= Mpad) return;
    Ab += (size_t)e * ((MODE == 0) ? 2097152 : 1048576);
    B0 += (size_t)e * ((size_t)KD * ND);
    if constexpr (DUALP) B1 += (size_t)e * ((size_t)KD * ND);
  }

  int lane = threadIdx.x & 63;
  int kb = lane & 31;              // B k-row this lane loads/writes
  int nh = (lane >> 5) * 16;       // B col half

  const float* Bp0 = B0 + n0 + nh;
  const float* Bp1 = (DUALP ? B1 + n0 + nh : B0 + n0 + 32 + nh);

  __shared__ __align__(16) char lds[8192];   // 2 parities x 2 mats x 32n x 32k fp16

  unsigned aoff[MF];
#pragma unroll
  for (int mf = 0; mf < MF; mf++)
    aoff[mf] = (row0 + mf * 16 + (lane & 15)) * 64 + ((lane >> 4) << 4);

  f32x4 acc0[MF][2], acc1[MF][2];
#pragma unroll
  for (int mf = 0; mf < MF; mf++)
#pragma unroll
    for (int f = 0; f < 2; f++) {
      acc0[mf][f] = (f32x4){0.f, 0.f, 0.f, 0.f};
      acc1[mf][f] = (f32x4){0.f, 0.f, 0.f, 0.f};
    }

  half8 af[MF];
  half8 bf0[2], bf1[2];
  f32x4 e0, e1, e2, e3, e4, e5, e6, e7;
  f32x4 o0, o1, o2, o3, o4, o5, o6, o7;

#define LOADB(tt, a0,a1,a2,a3,a4,a5,a6,a7) { \
    const float* r0 = Bp0 + (size_t)((tt) * 32 + kb) * ND; \
    const float* r1 = Bp1 + (size_t)((tt) * 32 + kb) * ND; \
    a0 = *(const f32x4*)(r0);      a1 = *(const f32x4*)(r0 + 4); \
    a2 = *(const f32x4*)(r0 + 8);  a3 = *(const f32x4*)(r0 + 12); \
    a4 = *(const f32x4*)(r1);      a5 = *(const f32x4*)(r1 + 4); \
    a6 = *(const f32x4*)(r1 + 8);  a7 = *(const f32x4*)(r1 + 12); }

#define WRITEB(par, a0,a1,a2,a3,a4,a5,a6,a7) { \
    char* base = lds + (par) * 4096; \
    _Pragma("unroll") \
    for (int c = 0; c < 16; c++) { \
      int nn = nh + c; \
      int off = nn * 64 + (((kb >> 3) ^ swz3(nn)) << 4) + (kb & 7) * 2; \
      f32x4 v0 = (c < 4) ? a0 : ((c < 8) ? a1 : ((c < 12) ? a2 : a3)); \
      f32x4 v1 = (c < 4) ? a4 : ((c < 8) ? a5 : ((c < 12) ? a6 : a7)); \
      *(f16*)(base + off) = (f16)v0[c & 3]; \
      *(f16*)(base + 2048 + off) = (f16)v1[c & 3]; \
    } }

#define BFREAD(par) { \
    _Pragma("unroll") \
    for (int f = 0; f < 2; f++) { \
      int nn = (lane & 15) + 16 * f; \
      int off = (par) * 4096 + nn * 64 + (((lane >> 4) ^ swz3(nn)) << 4); \
      bf0[f] = *(const half8*)(lds + off); \
      bf1[f] = *(const half8*)(lds + 2048 + off); \
    } }

#define LOADA(tt) { \
    _Pragma("unroll") \
    for (int mf = 0; mf < MF; mf++) \
      af[mf] = *(const half8*)(Ab + (size_t)(tt) * TS + aoff[mf]); }

#define DOMFMA() { \
    _Pragma("unroll") \
    for (int mf = 0; mf < MF; mf++) { \
      _Pragma("unroll") \
      for (int f = 0; f < 2; f++) { \
        acc0[mf][f] = __builtin_amdgcn_mfma_f32_16x16x32_f16(af[mf], bf0[f], acc0[mf][f], 0, 0, 0); \
        acc1[mf][f] = __builtin_amdgcn_mfma_f32_16x16x32_f16(af[mf], bf1[f], acc1[mf][f], 0, 0, 0); \
      } } }

  // Prologue: LDS0=tile0, O regs=tile1, E regs=tile2, af=tile0
  LOADB(0, e0,e1,e2,e3,e4,e5,e6,e7)
  LOADB(1, o0,o1,o2,o3,o4,o5,o6,o7)
  WRITEB(0, e0,e1,e2,e3,e4,e5,e6,e7)
  LOADA(0)
  LOADB(2, e0,e1,e2,e3,e4,e5,e6,e7)

  for (int s = 0; s < NK; s += 2) {
    // tile s (parity 0)
    BFREAD(0)
    WRITEB(1, o0,o1,o2,o3,o4,o5,o6,o7)            // publish tile s+1
    if (s + 3 < NK) LOADB(s + 3, o0,o1,o2,o3,o4,o5,o6,o7)
    DOMFMA()
    LOADA(s + 1)
    // tile s+1 (parity 1)
    BFREAD(1)
    if (s + 2 < NK) {
      WRITEB(0, e0,e1,e2,e3,e4,e5,e6,e7)          // publish tile s+2
      if (s + 4 < NK) LOADB(s + 4, e0,e1,e2,e3,e4,e5,e6,e7)
    }
    DOMFMA()
    if (s + 2 < NK) LOADA(s + 2)
  }
#undef LOADB
#undef WRITEB
#undef BFREAD
#undef LOADA
#undef DOMFMA

  // epilogue
  int koff = (lane >> 4) << 2;
  if constexpr (MODE == 0) {
    char* Hb = (char*)outp + (size_t)e * 1048576;
#pragma unroll
    for (int mf = 0; mf < MF; mf++)
#pragma unroll
      for (int j = 0; j < 4; j++) {
        int slot = row0 + mf * 16 + koff + j;
#pragma unroll
        for (int f = 0; f < 2; f++) {
          int col = n0 + f * 16 + (lane & 15);
          float g = acc0[mf][f][j], u = acc1[mf][f][j];
          float val = g / (1.f + expf(-g)) * u;
          *(f16*)(Hb + (size_t)(col >> 5) * 32768 + slot * 64 + (col & 31) * 2) = (f16)val;
        }
      }
  } else if constexpr (MODE == 1) {
    char* Hb = (char*)outp;
#pragma unroll
    for (int mf = 0; mf < MF; mf++)
#pragma unroll
      for (int j = 0; j < 4; j++) {
        int row = row0 + mf * 16 + koff + j;
#pragma unroll
        for (int f = 0; f < 2; f++) {
          int col = n0 + f * 16 + (lane & 15);
          float g = acc0[mf][f][j], u = acc1[mf][f][j];
          float val = g / (1.f + expf(-g)) * u;
          *(f16*)(Hb + (size_t)(col >> 5) * 131072 + row * 64 + (col & 31) * 2) = (f16)val;
        }
      }
  } else if constexpr (MODE == 2) {
    float* Of = (float*)outp;
    const int* tokp = tokL + e * CAP;
    const float* wtp = wtL + e * CAP;
#pragma unroll
    for (int mf = 0; mf < MF; mf++)
#pragma unroll
      for (int j = 0; j < 4; j++) {
        int slot = row0 + mf * 16 + koff + j;
        if (slot < Mcur) {
          int tk = tokp[slot];
          float w = wtp[slot];
#pragma unroll
          for (int f = 0; f < 2; f++) {
            int col = n0 + f * 16 + (lane & 15);
            atomicAdd(Of + (size_t)tk * HDIM + col, acc0[mf][f][j] * w);
            atomicAdd(Of + (size_t)tk * HDIM + col + 32, acc1[mf][f][j] * w);
          }
        }
      }
  } else {
    float* Of = (float*)outp;
#pragma unroll
    for (int mf = 0; mf < MF; mf++)
#pragma unroll
      for (int j = 0; j < 4; j++) {
        int row = row0 + mf * 16 + koff + j;
#pragma unroll
        for (int f = 0; f < 2; f++) {
          int col = n0 + f * 16 + (lane & 15);
          Of[(size_t)row * HDIM + col] = acc0[mf][f][j];
          Of[(size_t)row * HDIM + col + 32] = acc1[mf][f][j];
        }
      }
  }
}

// ---------------- launch ----------------
extern "C" void kernel_launch(void* const* d_in, const int* in_sizes, int n_in,
                              void* d_out, int out_size, void* d_ws, size_t ws_size,
                              hipStream_t stream) {
  const float* x  = (const float*)d_in[0];
  const float* gw = (const float*)d_in[1];
  const float* gb = (const float*)d_in[2];
  const float* w1 = (const float*)d_in[3];
  const float* w2 = (const float*)d_in[4];
  const float* w3 = (const float*)d_in[5];
  const float* sg = (const float*)d_in[6];
  const float* su = (const float*)d_in[7];
  const float* sd = (const float*)d_in[8];
  float* out = (float*)d_out;
  char* ws = (char*)d_ws;

  f16*   xbt = (f16*)(ws);                 // 8 MB  k-chunked x fp16
  f16*   hs  = (f16*)(ws + 8388608);       // 8 MB  k-chunked shared-mid
  f16*   hbuf= (f16*)(ws + 16777216);      // 32 MB k-chunked routed-mid
  f16*   xg  = (f16*)(ws + 50331648);      // 64 MB compact gathered A
  int*   tok = (int*)(ws + 117440512);
  float* wt  = (float*)(ws + 117506048);
  int*   tidx= (int*)(ws + 117571584);
  float* tw  = (float*)(ws + 117604352);
  int*   cnt = (int*)(ws + 117637120);

  convert_kernel<<<2048, 256, 0, stream>>>(x, xbt);
  gate_kernel<<<2048, 256, 0, stream>>>(x, gw, gb, tidx, tw);
  dispatch_kernel<<<32, 256, 0, stream>>>(tidx, tw, tok, wt, cnt);
  gather_kernel<<<2048, 256, 0, stream>>>(xbt, tok, cnt, xg);

  // routed up: hbuf = silu(Xg@w1)*(Xg@w3)   grid = 32e x 32n x 4rw
  gemm_kernel<0><<<4096, 64, 0, stream>>>(xg, w1, w3, hbuf, tok, wt, cnt);
  // shared up: hs = silu(x@sg)*(x@su)       grid = 64n x 32rw
  gemm_kernel<1><<<2048, 64, 0, stream>>>(xbt, sg, su, hs, nullptr, nullptr, nullptr);
  // shared down: out = hs @ sd              grid = 32n x 32rw
  gemm_kernel<3><<<1024, 64, 0, stream>>>(hs, sd, nullptr, out, nullptr, nullptr, nullptr);
  // routed down: out += w * (hbuf @ w2)     grid = 32e x 32n x 4rw
  gemm_kernel<2><<<4096, 64, 0, stream>>>(hbuf, w2, nullptr, out, tok, wt, cnt);
}

// Round 9
// 604.308 us; speedup vs baseline: 2.3594x; 2.3594x over previous
//
#include <hip/hip_runtime.h>
#include <stdint.h>
#include <math.h>

#define NTOK 2048
#define HDIM 2048
#define FDIM 1024
#define NEXP 32
#define TOPK 4
#define NGRP 4
#define CAP  512

typedef _Float16 f16;
typedef _Float16 half8 __attribute__((ext_vector_type(8)));
typedef float f32x4 __attribute__((ext_vector_type(4)));

__device__ __forceinline__ int swz3(int n) { return (n ^ (n >> 2)) & 3; }

// ---------------- convert x fp32 [2048][2048] -> xbt fp16 k-chunked [64][2048][32] ----------------
__global__ __launch_bounds__(256) void convert_kernel(const float* __restrict__ x,
                                                      f16* __restrict__ xbt) {
  int i = blockIdx.x * 256 + threadIdx.x;
  int r = i >> 8;
  int c8 = (i & 255) << 3;
  const float* p = x + (size_t)r * HDIM + c8;
  f32x4 a = *(const f32x4*)p;
  f32x4 b = *(const f32x4*)(p + 4);
  half8 v;
  v[0] = (f16)a[0]; v[1] = (f16)a[1]; v[2] = (f16)a[2]; v[3] = (f16)a[3];
  v[4] = (f16)b[0]; v[5] = (f16)b[1]; v[6] = (f16)b[2]; v[7] = (f16)b[3];
  int t = c8 >> 5;
  *(half8*)((char*)xbt + (size_t)t * 131072 + r * 64 + (c8 & 31) * 2) = v;
}

// ---------------- gate ----------------
__global__ __launch_bounds__(256) void gate_kernel(const float* __restrict__ x,
                                                   const float* __restrict__ gw,
                                                   const float* __restrict__ gb,
                                                   int* __restrict__ tidx,
                                                   float* __restrict__ tw) {
  int t = blockIdx.x;
  int tid = threadIdx.x;
  int e = tid >> 3, p = tid & 7;
  const f32x4* xr = (const f32x4*)(x + (size_t)t * HDIM);
  const f32x4* wr = (const f32x4*)(gw + (size_t)e * HDIM);
  float s = 0.f;
  for (int c = 0; c < 64; c++) {
    f32x4 a = xr[p + c * 8], w = wr[p + c * 8];
    s += a[0] * w[0] + a[1] * w[1] + a[2] * w[2] + a[3] * w[3];
  }
  s += __shfl_down(s, 4, 8);
  s += __shfl_down(s, 2, 8);
  s += __shfl_down(s, 1, 8);
  __shared__ float lg[NEXP];
  if (p == 0) lg[e] = s;
  __syncthreads();
  if (tid == 0) {
    float sc[NEXP], scb[NEXP];
    for (int i = 0; i < NEXP; i++) {
      sc[i] = 1.f / (1.f + expf(-lg[i]));
      scb[i] = sc[i] + gb[i];
    }
    float gs[NGRP];
    for (int g = 0; g < NGRP; g++) {
      float m1 = -1e30f, m2 = -1e30f;
      for (int j = 0; j < 8; j++) {
        float v = scb[g * 8 + j];
        if (v > m1) { m2 = m1; m1 = v; }
        else if (v > m2) m2 = v;
      }
      gs[g] = m1 + m2;
    }
    int g1 = 0; float bv = gs[0];
    for (int g = 1; g < NGRP; g++) if (gs[g] > bv) { bv = gs[g]; g1 = g; }
    int g2 = -1; bv = -1e30f;
    for (int g = 0; g < NGRP; g++) if (g != g1 && gs[g] > bv) { bv = gs[g]; g2 = g; }
    float cand[NEXP];
    for (int i = 0; i < NEXP; i++) {
      int g = i >> 3;
      cand[i] = (g == g1 || g == g2) ? scb[i] : 0.0f;
    }
    int isel[TOPK]; float wsel[TOPK]; float wsum = 0.f;
    bool used[NEXP] = {};
    for (int k = 0; k < TOPK; k++) {
      int best = 0; float bw = -1e30f;
      for (int i = 0; i < NEXP; i++)
        if (!used[i] && cand[i] > bw) { bw = cand[i]; best = i; }
      used[best] = true;
      isel[k] = best;
      wsel[k] = sc[best];
      wsum += wsel[k];
    }
    float inv = 2.0f / (wsum + 1e-20f);
    for (int k = 0; k < TOPK; k++) {
      tidx[t * TOPK + k] = isel[k];
      tw[t * TOPK + k] = wsel[k] * inv;
    }
  }
}

// ---------------- dispatch ----------------
__global__ __launch_bounds__(256) void dispatch_kernel(const int* __restrict__ tidx,
                                                       const float* __restrict__ tw,
                                                       int* __restrict__ tok,
                                                       float* __restrict__ wt,
                                                       int* __restrict__ cnt) {
  int e = blockIdx.x, tid = threadIdx.x, wv = tid >> 6, lane = tid & 63;
  __shared__ int wsum[4];
  __shared__ int sbase;
  if (tid == 0) sbase = 0;
  __syncthreads();
  for (int c = 0; c < (NTOK * TOPK) / 256; c++) {
    int i = c * 256 + tid;
    int fe = tidx[i];
    bool flag = (fe == e);
    unsigned long long b = __ballot(flag ? 1 : 0);
    int lr = __popcll(b & ((1ull << lane) - 1ull));
    if (lane == 0) wsum[wv] = __popcll(b);
    __syncthreads();
    int off = 0;
    for (int w2 = 0; w2 < wv; w2++) off += wsum[w2];
    int tot = wsum[0] + wsum[1] + wsum[2] + wsum[3];
    int base = sbase;
    if (flag) {
      int pos = base + off + lr;
      if (pos < CAP) {
        tok[e * CAP + pos] = i >> 2;
        wt[e * CAP + pos] = tw[i];
      }
    }
    __syncthreads();
    if (tid == 0) sbase = base + tot;
  }
  __syncthreads();
  if (tid == 0) cnt[e] = min(sbase, CAP);
}

// ---------------- gather: xg[e][t][slot][32k] = xbt[t][tok[e][slot]] (real slots only) ----------------
__global__ __launch_bounds__(256) void gather_kernel(const f16* __restrict__ xbt,
                                                     const int* __restrict__ tok,
                                                     const int* __restrict__ cnt,
                                                     f16* __restrict__ xg) {
  int bid = blockIdx.x;
  int t = bid & 63, e = bid >> 6;
  int cn = cnt[e];
  int tid = threadIdx.x;
  char* dst = (char*)xg + (size_t)e * 2097152 + (size_t)t * 32768;
  const char* srcb = (const char*)xbt + (size_t)t * 131072;
  for (int s = tid; s < cn; s += 256) {
    const uint4* sp = (const uint4*)(srcb + (size_t)tok[e * CAP + s] * 64);
    uint4 v0 = sp[0], v1 = sp[1], v2 = sp[2], v3 = sp[3];
    uint4* dp = (uint4*)(dst + s * 64);
    dp[0] = v0; dp[1] = v1; dp[2] = v2; dp[3] = v3;
  }
}

// ---------------- depth-4 counted pipeline MFMA GEMM (4-wave block) ----------------
// B global->regs (4 named sets = 4-tile lead) -> fp16 LDS dbuf; one barrier/tile.
// A global->VGPR frags (L2-hot k-chunked), 1-tile lead. Compiler emits exact
// counted vmcnt from reg dataflow (never drains the deep B queue).
// MODE 0: routed up (dual w1/w3, A=xg[e], silu-mul -> hbuf k-chunked)
// MODE 1: shared up (dual sg/su, A=xbt, -> hs k-chunked)
// MODE 2: routed down (w2 as two 32-col halves, A=hbuf[e], atomicAdd out)
// MODE 3: shared down (sd, A=hs, plain store out)
template<int MODE>
__global__ __launch_bounds__(256, 2)
void gemm_kernel(const f16* __restrict__ Ag, const float* __restrict__ B0g,
                 const float* __restrict__ B1g, void* __restrict__ outp,
                 const int* __restrict__ tokL, const float* __restrict__ wtL,
                 const int* __restrict__ cntP) {
  constexpr bool ROUTED = (MODE == 0 || MODE == 2);
  constexpr bool DUAL = (MODE <= 1);
  constexpr bool WIDE = (MODE == 2);
  constexpr bool SINGLE = (MODE == 3);
  constexpr int MF = ROUTED ? 6 : 4;          // frags/wave; WM = 16*MF
  constexpr int WM = MF * 16;
  constexpr int BM = WM * 4;                  // 384 routed, 256 shared
  constexpr int KD = (MODE == 2) ? 1024 : 2048;
  constexpr int NK = KD / 32;
  constexpr int ND = (MODE == 0) ? 1024 : 2048;
  constexpr size_t TS = ROUTED ? 32768 : 131072;   // A k-chunk byte stride
  constexpr int LDSB = (SINGLE ? 1 : 2) * 2048;    // bytes per parity

  int bid = blockIdx.x;
  int tid = threadIdx.x, lane = tid & 63, wv = tid >> 6;

  int e = 0, mstart = 0, n0;
  if constexpr (ROUTED) {
    int x = bid & 7, j = bid >> 3;
    e = x + 8 * (j >> 5);                     // one expert at a time per XCD
    n0 = (j & 31) * ((MODE == 0) ? 32 : 64);
  } else {
    mstart = (bid & 7) * 256;                 // m-tile pinned to XCD (A L2-hot)
    n0 = (bid >> 3) * 32;
  }

  const char* Ab = (const char*)Ag;
  const float* B0 = B0g;
  const float* B1 = B1g;
  int Mcur = NTOK;
  if constexpr (ROUTED) {
    Mcur = cntP[e];
    Ab += (size_t)e * ((MODE == 0) ? 2097152 : 1048576);
    B0 += (size_t)e * ((size_t)KD * ND);
    if constexpr (DUAL) B1 += (size_t)e * ((size_t)KD * ND);
  }

  __shared__ __align__(16) char lds[2 * LDSB];

  int kb = tid >> 3;                // B k-row 0..31
  int nb4 = (tid & 7) * 4;          // B col base within 32
  const float* Bk0 = B0 + (size_t)kb * ND + n0 + nb4;
  const float* Bk1 = DUAL ? (B1 + (size_t)kb * ND + n0 + nb4) : nullptr;

  f32x4 sA0, sA1, sB0, sB1, sC0, sC1, sD0, sD1;   // 4 B prefetch sets
  half8 af[MF];
  half8 bf0[2];
  half8 bf1[SINGLE ? 1 : 2];

#define LOADB(tt, X0, X1) { \
    const float* _p = Bk0 + (size_t)(tt) * (32 * ND); \
    X0 = *(const f32x4*)_p; \
    if constexpr (DUAL) X1 = *(const f32x4*)(Bk1 + (size_t)(tt) * (32 * ND)); \
    else if constexpr (WIDE) X1 = *(const f32x4*)(_p + 32); }

#define WRITEB(X0, X1, par) { \
    char* _b = lds + (par) * LDSB; \
    _Pragma("unroll") \
    for (int _q = 0; _q < 4; _q++) { \
      int _n = nb4 + _q; \
      int _off = _n * 64 + (((kb >> 3) ^ swz3(_n)) << 4) + (kb & 7) * 2; \
      *(f16*)(_b + _off) = (f16)X0[_q]; \
      if constexpr (!SINGLE) *(f16*)(_b + 2048 + _off) = (f16)X1[_q]; \
    } }

#define BFREAD(par) { \
    _Pragma("unroll") \
    for (int _f = 0; _f < 2; _f++) { \
      int _n = _f * 16 + (lane & 15); \
      int _off = (par) * LDSB + _n * 64 + (((lane >> 4) ^ swz3(_n)) << 4); \
      bf0[_f] = *(const half8*)(lds + _off); \
      if constexpr (!SINGLE) bf1[_f] = *(const half8*)(lds + 2048 + _off); \
    } }

#define LOADA(tt) { \
    _Pragma("unroll") \
    for (int _m = 0; _m < MF; _m++) \
      af[_m] = *(const half8*)(Ab + (size_t)(tt) * TS + aoff[_m]); }

#define DOMFMA() { \
    _Pragma("unroll") \
    for (int _m = 0; _m < MF; _m++) { \
      _Pragma("unroll") \
      for (int _f = 0; _f < 2; _f++) { \
        acc0[_m][_f] = __builtin_amdgcn_mfma_f32_16x16x32_f16(af[_m], bf0[_f], acc0[_m][_f], 0, 0, 0); \
        if constexpr (!SINGLE) \
          acc1[_m][_f] = __builtin_amdgcn_mfma_f32_16x16x32_f16(af[_m], bf1[_f], acc1[_m][_f], 0, 0, 0); \
      } } }

#define SYNC() { asm volatile("s_waitcnt lgkmcnt(0)" ::: "memory"); __builtin_amdgcn_s_barrier(); }

  int m0 = mstart;
  while (true) {
    unsigned aoff[MF];
#pragma unroll
    for (int mf = 0; mf < MF; mf++) {
      int row = m0 + wv * WM + mf * 16 + (lane & 15);
      aoff[mf] = row * 64 + ((lane >> 4) << 4);
    }

    f32x4 acc0[MF][2];
    f32x4 acc1[SINGLE ? 1 : MF][SINGLE ? 1 : 2];
#pragma unroll
    for (int mf = 0; mf < MF; mf++)
#pragma unroll
      for (int f = 0; f < 2; f++) acc0[mf][f] = (f32x4){0.f, 0.f, 0.f, 0.f};
    if constexpr (!SINGLE) {
#pragma unroll
      for (int mf = 0; mf < MF; mf++)
#pragma unroll
        for (int f = 0; f < 2; f++) acc1[mf][f] = (f32x4){0.f, 0.f, 0.f, 0.f};
    }

    // Prologue: fill 4 B sets, publish tile 0, prefetch A(0).
    LOADB(0, sA0, sA1)
    LOADB(1, sB0, sB1)
    LOADB(2, sC0, sC1)
    LOADB(3, sD0, sD1)
    WRITEB(sA0, sA1, 0)
    LOADA(0)
    SYNC()

    for (int u = 0; u < NK; u += 4) {
      // tile u (par 0): publish u+1, refill set A with u+4
      BFREAD(0)
      WRITEB(sB0, sB1, 1)
      if (u + 4 < NK) LOADB(u + 4, sA0, sA1)
      DOMFMA()
      LOADA(u + 1)
      SYNC()
      // tile u+1 (par 1)
      BFREAD(1)
      WRITEB(sC0, sC1, 0)
      if (u + 5 < NK) LOADB(u + 5, sB0, sB1)
      DOMFMA()
      LOADA(u + 2)
      SYNC()
      // tile u+2 (par 0)
      BFREAD(0)
      WRITEB(sD0, sD1, 1)
      if (u + 6 < NK) LOADB(u + 6, sC0, sC1)
      DOMFMA()
      LOADA(u + 3)
      SYNC()
      // tile u+3 (par 1)
      BFREAD(1)
      if (u + 4 < NK) WRITEB(sA0, sA1, 0)
      if (u + 7 < NK) LOADB(u + 7, sD0, sD1)
      DOMFMA()
      if (u + 4 < NK) {
        LOADA(u + 4)
        SYNC()
      }
    }

    // epilogue for this m-pass
    int koff = (lane >> 4) << 2;
    if constexpr (MODE == 0) {
      char* Hb = (char*)outp + (size_t)e * 1048576;
#pragma unroll
      for (int mf = 0; mf < MF; mf++)
#pragma unroll
        for (int j = 0; j < 4; j++) {
          int slot = m0 + wv * WM + mf * 16 + koff + j;
          if (slot < Mcur) {
#pragma unroll
            for (int f = 0; f < 2; f++) {
              int col = n0 + f * 16 + (lane & 15);
              float g = acc0[mf][f][j], u = acc1[mf][f][j];
              float val = g / (1.f + expf(-g)) * u;
              *(f16*)(Hb + (size_t)(col >> 5) * 32768 + slot * 64 + (col & 31) * 2) = (f16)val;
            }
          }
        }
    } else if constexpr (MODE == 1) {
      char* Hb = (char*)outp;
#pragma unroll
      for (int mf = 0; mf < MF; mf++)
#pragma unroll
        for (int j = 0; j < 4; j++) {
          int row = m0 + wv * WM + mf * 16 + koff + j;
#pragma unroll
          for (int f = 0; f < 2; f++) {
            int col = n0 + f * 16 + (lane & 15);
            float g = acc0[mf][f][j], u = acc1[mf][f][j];
            float val = g / (1.f + expf(-g)) * u;
            *(f16*)(Hb + (size_t)(col >> 5) * 131072 + row * 64 + (col & 31) * 2) = (f16)val;
          }
        }
    } else if constexpr (MODE == 2) {
      float* Of = (float*)outp;
      const int* tokp = tokL + e * CAP;
      const float* wtp = wtL + e * CAP;
#pragma unroll
      for (int mf = 0; mf < MF; mf++)
#pragma unroll
        for (int j = 0; j < 4; j++) {
          int slot = m0 + wv * WM + mf * 16 + koff + j;
          if (slot < Mcur) {
            int tk = tokp[slot];
            float w = wtp[slot];
#pragma unroll
            for (int f = 0; f < 2; f++) {
              int col = n0 + f * 16 + (lane & 15);
              atomicAdd(Of + (size_t)tk * HDIM + col, acc0[mf][f][j] * w);
              atomicAdd(Of + (size_t)tk * HDIM + col + 32, acc1[mf][f][j] * w);
            }
          }
        }
    } else {
      float* Of = (float*)outp;
#pragma unroll
      for (int mf = 0; mf < MF; mf++)
#pragma unroll
        for (int j = 0; j < 4; j++) {
          int row = m0 + wv * WM + mf * 16 + koff + j;
#pragma unroll
          for (int f = 0; f < 2; f++) {
            int col = n0 + f * 16 + (lane & 15);
            Of[(size_t)row * HDIM + col] = acc0[mf][f][j];
          }
        }
    }

    m0 += BM;
    if (!(ROUTED && m0 < Mcur)) break;
  }

#undef LOADB
#undef WRITEB
#undef BFREAD
#undef LOADA
#undef DOMFMA
#undef SYNC
}

// ---------------- launch ----------------
extern "C" void kernel_launch(void* const* d_in, const int* in_sizes, int n_in,
                              void* d_out, int out_size, void* d_ws, size_t ws_size,
                              hipStream_t stream) {
  const float* x  = (const float*)d_in[0];
  const float* gw = (const float*)d_in[1];
  const float* gb = (const float*)d_in[2];
  const float* w1 = (const float*)d_in[3];
  const float* w2 = (const float*)d_in[4];
  const float* w3 = (const float*)d_in[5];
  const float* sg = (const float*)d_in[6];
  const float* su = (const float*)d_in[7];
  const float* sd = (const float*)d_in[8];
  float* out = (float*)d_out;
  char* ws = (char*)d_ws;

  f16*   xbt = (f16*)(ws);                 // 8 MB  k-chunked x fp16
  f16*   hs  = (f16*)(ws + 8388608);       // 8 MB  k-chunked shared-mid
  f16*   hbuf= (f16*)(ws + 16777216);      // 32 MB k-chunked routed-mid
  f16*   xg  = (f16*)(ws + 50331648);      // 64 MB compact gathered A
  int*   tok = (int*)(ws + 117440512);
  float* wt  = (float*)(ws + 117506048);
  int*   tidx= (int*)(ws + 117571584);
  float* tw  = (float*)(ws + 117604352);
  int*   cnt = (int*)(ws + 117637120);

  convert_kernel<<<2048, 256, 0, stream>>>(x, xbt);
  gate_kernel<<<2048, 256, 0, stream>>>(x, gw, gb, tidx, tw);
  dispatch_kernel<<<32, 256, 0, stream>>>(tidx, tw, tok, wt, cnt);
  gather_kernel<<<2048, 256, 0, stream>>>(xbt, tok, cnt, xg);

  // routed up: hbuf = silu(Xg@w1)*(Xg@w3)   grid = 32e x 32n
  gemm_kernel<0><<<1024, 256, 0, stream>>>(xg, w1, w3, hbuf, tok, wt, cnt);
  // shared up: hs = silu(x@sg)*(x@su)       grid = 8m x 64n
  gemm_kernel<1><<<512, 256, 0, stream>>>(xbt, sg, su, hs, nullptr, nullptr, nullptr);
  // shared down: out = hs @ sd              grid = 8m x 64n
  gemm_kernel<3><<<512, 256, 0, stream>>>(hs, sd, nullptr, out, nullptr, nullptr, nullptr);
  // routed down: out += w * (hbuf @ w2)     grid = 32e x 32n
  gemm_kernel<2><<<1024, 256, 0, stream>>>(hbuf, w2, nullptr, out, tok, wt, cnt);
}

// Round 10
// 598.489 us; speedup vs baseline: 2.3823x; 1.0097x over previous
//
#include <hip/hip_runtime.h>
#include <stdint.h>
#include <math.h>

#define NTOK 2048
#define HDIM 2048
#define FDIM 1024
#define NEXP 32
#define TOPK 4
#define NGRP 4
#define CAP  512

typedef _Float16 f16;
typedef _Float16 half8 __attribute__((ext_vector_type(8)));
typedef _Float16 half2v __attribute__((ext_vector_type(2)));
typedef float f32x4 __attribute__((ext_vector_type(4)));

__device__ __forceinline__ int swz3(int n) { return (n ^ (n >> 2)) & 3; }

// ---------------- fused gate + convert (x row -> logits AND k-chunked fp16) ----------------
__global__ __launch_bounds__(256) void gateconv_kernel(const float* __restrict__ x,
                                                       const float* __restrict__ gw,
                                                       const float* __restrict__ gb,
                                                       int* __restrict__ tidx,
                                                       float* __restrict__ tw,
                                                       f16* __restrict__ xbt) {
  int t = blockIdx.x;
  int tid = threadIdx.x;
  int e = tid >> 3, p = tid & 7;
  const f32x4* xr = (const f32x4*)(x + (size_t)t * HDIM);
  const f32x4* wr = (const f32x4*)(gw + (size_t)e * HDIM);
  float s = 0.f;
  for (int c = 0; c < 64; c++) {
    f32x4 a = xr[p + c * 8], w = wr[p + c * 8];
    s += a[0] * w[0] + a[1] * w[1] + a[2] * w[2] + a[3] * w[3];
  }
  s += __shfl_down(s, 4, 8);
  s += __shfl_down(s, 2, 8);
  s += __shfl_down(s, 1, 8);
  __shared__ float lg[NEXP];
  if (p == 0) lg[e] = s;

  // convert this token's row (L1-hot) to k-chunked fp16
  {
    int c8 = tid * 8;
    const float* pp = x + (size_t)t * HDIM + c8;
    f32x4 a = *(const f32x4*)pp;
    f32x4 b = *(const f32x4*)(pp + 4);
    half8 v;
    v[0] = (f16)a[0]; v[1] = (f16)a[1]; v[2] = (f16)a[2]; v[3] = (f16)a[3];
    v[4] = (f16)b[0]; v[5] = (f16)b[1]; v[6] = (f16)b[2]; v[7] = (f16)b[3];
    *(half8*)((char*)xbt + (size_t)(c8 >> 5) * 131072 + t * 64 + (c8 & 31) * 2) = v;
  }

  __syncthreads();
  if (tid == 0) {
    float sc[NEXP], scb[NEXP];
    for (int i = 0; i < NEXP; i++) {
      sc[i] = 1.f / (1.f + expf(-lg[i]));
      scb[i] = sc[i] + gb[i];
    }
    float gs[NGRP];
    for (int g = 0; g < NGRP; g++) {
      float m1 = -1e30f, m2 = -1e30f;
      for (int j = 0; j < 8; j++) {
        float v = scb[g * 8 + j];
        if (v > m1) { m2 = m1; m1 = v; }
        else if (v > m2) m2 = v;
      }
      gs[g] = m1 + m2;
    }
    int g1 = 0; float bv = gs[0];
    for (int g = 1; g < NGRP; g++) if (gs[g] > bv) { bv = gs[g]; g1 = g; }
    int g2 = -1; bv = -1e30f;
    for (int g = 0; g < NGRP; g++) if (g != g1 && gs[g] > bv) { bv = gs[g]; g2 = g; }
    float cand[NEXP];
    for (int i = 0; i < NEXP; i++) {
      int g = i >> 3;
      cand[i] = (g == g1 || g == g2) ? scb[i] : 0.0f;
    }
    int isel[TOPK]; float wsel[TOPK]; float wsum = 0.f;
    bool used[NEXP] = {};
    for (int k = 0; k < TOPK; k++) {
      int best = 0; float bw = -1e30f;
      for (int i = 0; i < NEXP; i++)
        if (!used[i] && cand[i] > bw) { bw = cand[i]; best = i; }
      used[best] = true;
      isel[k] = best;
      wsel[k] = sc[best];
      wsum += wsel[k];
    }
    float inv = 2.0f / (wsum + 1e-20f);
    for (int k = 0; k < TOPK; k++) {
      tidx[t * TOPK + k] = isel[k];
      tw[t * TOPK + k] = wsel[k] * inv;
    }
  }
}

// ---------------- dispatch ----------------
__global__ __launch_bounds__(256) void dispatch_kernel(const int* __restrict__ tidx,
                                                       const float* __restrict__ tw,
                                                       int* __restrict__ tok,
                                                       float* __restrict__ wt,
                                                       int* __restrict__ cnt) {
  int e = blockIdx.x, tid = threadIdx.x, wv = tid >> 6, lane = tid & 63;
  __shared__ int wsum[4];
  __shared__ int sbase;
  if (tid == 0) sbase = 0;
  __syncthreads();
  for (int c = 0; c < (NTOK * TOPK) / 256; c++) {
    int i = c * 256 + tid;
    int fe = tidx[i];
    bool flag = (fe == e);
    unsigned long long b = __ballot(flag ? 1 : 0);
    int lr = __popcll(b & ((1ull << lane) - 1ull));
    if (lane == 0) wsum[wv] = __popcll(b);
    __syncthreads();
    int off = 0;
    for (int w2 = 0; w2 < wv; w2++) off += wsum[w2];
    int tot = wsum[0] + wsum[1] + wsum[2] + wsum[3];
    int base = sbase;
    if (flag) {
      int pos = base + off + lr;
      if (pos < CAP) {
        tok[e * CAP + pos] = i >> 2;
        wt[e * CAP + pos] = tw[i];
      }
    }
    __syncthreads();
    if (tid == 0) sbase = base + tot;
  }
  __syncthreads();
  if (tid == 0) cnt[e] = min(sbase, CAP);
}

// ---------------- gather: xg[e][kt][slot][32k] = xbt[kt][tok[e][slot]] ----------------
__global__ __launch_bounds__(256) void gather_kernel(const f16* __restrict__ xbt,
                                                     const int* __restrict__ tok,
                                                     const int* __restrict__ cnt,
                                                     f16* __restrict__ xg) {
  int bid = blockIdx.x;
  int t = bid & 63, e = bid >> 6;
  int cn = cnt[e];
  int tid = threadIdx.x;
  char* dst = (char*)xg + (size_t)e * 2097152 + (size_t)t * 32768;
  const char* srcb = (const char*)xbt + (size_t)t * 131072;
  for (int s = tid; s < cn; s += 256) {
    const uint4* sp = (const uint4*)(srcb + (size_t)tok[e * CAP + s] * 64);
    uint4 v0 = sp[0], v1 = sp[1], v2 = sp[2], v3 = sp[3];
    uint4* dp = (uint4*)(dst + s * 64);
    dp[0] = v0; dp[1] = v1; dp[2] = v2; dp[3] = v3;
  }
}

// ---------------- routed GEMM: 2-wave blocks, 4 independent domains/CU ----------------
// MODE 0: routed up (dual w1/w3, A=xg[e], silu-mul -> hbuf k-chunked)
// MODE 2: routed down (w2 as two 32-col halves, A=hbuf[e], atomicAdd out)
template<int MODE>
__global__ __launch_bounds__(128, 2)
void gemm2_kernel(const f16* __restrict__ Ag, const float* __restrict__ B0g,
                  const float* __restrict__ B1g, void* __restrict__ outp,
                  const int* __restrict__ tokL, const float* __restrict__ wtL,
                  const int* __restrict__ cntP) {
  constexpr bool UP = (MODE == 0);
  constexpr int KD = UP ? 2048 : 1024;
  constexpr int NK = KD / 32;
  constexpr int ND = UP ? 1024 : 2048;

  int bid = blockIdx.x;
  // decode: 3b XCD-pinned expert-low | 2b expert-high | 1b m | 5b n
  int e = (bid & 7) + (((bid >> 3) & 3) << 3);
  int m0 = ((bid >> 5) & 1) * 256;
  int n0 = (bid >> 6) * (UP ? 32 : 64);

  int cnt_e = cntP[e];
  if (m0 >= cnt_e) return;

  const char* Ab = (const char*)Ag + (size_t)e * (UP ? 2097152 : 1048576);
  const float* B0 = B0g + (size_t)e * ((size_t)KD * ND);
  const float* B1 = UP ? (B1g + (size_t)e * ((size_t)KD * ND)) : nullptr;

  int tid = threadIdx.x, lane = tid & 63, wv = tid >> 6;

  // B staging map: thread covers k-pair kp, 4 cols n4 (both mats)
  int n4 = (tid & 7) * 4;
  int kp = (tid >> 3) * 2;
  const float* Bk0 = B0 + (size_t)kp * ND + n0 + n4;
  const float* Bk1 = UP ? (B1 + (size_t)kp * ND + n0 + n4)
                        : (B0 + (size_t)kp * ND + n0 + 32 + n4);

  __shared__ __align__(16) char lds[8192];   // 2 par x (2 mats x 32n x 32k fp16)

  unsigned aoff[8];
#pragma unroll
  for (int mf = 0; mf < 8; mf++) {
    int row = m0 + wv * 128 + mf * 16 + (lane & 15);
    aoff[mf] = row * 64 + ((lane >> 4) << 4);
  }

  f32x4 acc0[8][2], acc1[8][2];
#pragma unroll
  for (int mf = 0; mf < 8; mf++)
#pragma unroll
    for (int f = 0; f < 2; f++) {
      acc0[mf][f] = (f32x4){0.f, 0.f, 0.f, 0.f};
      acc1[mf][f] = (f32x4){0.f, 0.f, 0.f, 0.f};
    }

  half8 af[8];
  half8 bf0[2], bf1[2];
  f32x4 E0, E1, E2, E3, O0, O1, O2, O3;

#define LOADB(tt, S0, S1, S2, S3) { \
    size_t _b = (size_t)(tt) * (32 * ND); \
    S0 = *(const f32x4*)(Bk0 + _b); \
    S1 = *(const f32x4*)(Bk0 + _b + ND); \
    S2 = *(const f32x4*)(Bk1 + _b); \
    S3 = *(const f32x4*)(Bk1 + _b + ND); }

#define WRITEB(S0, S1, S2, S3, par) { \
    char* _base = lds + (par) * 4096; \
    _Pragma("unroll") \
    for (int _q = 0; _q < 4; _q++) { \
      int _n = n4 + _q; \
      int _off = _n * 64 + (((kp >> 3) ^ swz3(_n)) << 4) + (kp & 7) * 2; \
      half2v _h0; _h0[0] = (f16)S0[_q]; _h0[1] = (f16)S1[_q]; \
      *(half2v*)(_base + _off) = _h0; \
      half2v _h1; _h1[0] = (f16)S2[_q]; _h1[1] = (f16)S3[_q]; \
      *(half2v*)(_base + 2048 + _off) = _h1; \
    } }

#define BFREAD(par) { \
    _Pragma("unroll") \
    for (int _f = 0; _f < 2; _f++) { \
      int _n = _f * 16 + (lane & 15); \
      int _off = (par) * 4096 + _n * 64 + (((lane >> 4) ^ swz3(_n)) << 4); \
      bf0[_f] = *(const half8*)(lds + _off); \
      bf1[_f] = *(const half8*)(lds + 2048 + _off); \
    } }

#define LOADA(tt) { \
    _Pragma("unroll") \
    for (int _m = 0; _m < 8; _m++) \
      af[_m] = *(const half8*)(Ab + (size_t)(tt) * 32768 + aoff[_m]); }

#define DOMFMA() { \
    _Pragma("unroll") \
    for (int _m = 0; _m < 8; _m++) { \
      _Pragma("unroll") \
      for (int _f = 0; _f < 2; _f++) { \
        acc0[_m][_f] = __builtin_amdgcn_mfma_f32_16x16x32_f16(af[_m], bf0[_f], acc0[_m][_f], 0, 0, 0); \
        acc1[_m][_f] = __builtin_amdgcn_mfma_f32_16x16x32_f16(af[_m], bf1[_f], acc1[_m][_f], 0, 0, 0); \
      } } }

#define SYNC() { asm volatile("s_waitcnt lgkmcnt(0)" ::: "memory"); __builtin_amdgcn_s_barrier(); }

  // Prologue
  LOADB(0, E0, E1, E2, E3)
  LOADB(1, O0, O1, O2, O3)
  WRITEB(E0, E1, E2, E3, 0)
  LOADA(0)
  SYNC()

  for (int t = 0; t < NK; t += 2) {
    // tile t (par 0)
    BFREAD(0)
    WRITEB(O0, O1, O2, O3, 1)                 // publish t+1
    if (t + 2 < NK) LOADB(t + 2, E0, E1, E2, E3)
    DOMFMA()
    LOADA(t + 1)
    SYNC()
    // tile t+1 (par 1)
    BFREAD(1)
    if (t + 2 < NK) {
      WRITEB(E0, E1, E2, E3, 0)               // publish t+2
      if (t + 3 < NK) LOADB(t + 3, O0, O1, O2, O3)
    }
    DOMFMA()
    if (t + 2 < NK) {
      LOADA(t + 2)
      SYNC()
    }
  }

#undef LOADB
#undef WRITEB
#undef BFREAD
#undef LOADA
#undef DOMFMA
#undef SYNC

  int koff = (lane >> 4) << 2;
  if constexpr (MODE == 0) {
    char* Hb = (char*)outp + (size_t)e * 1048576;
#pragma unroll
    for (int mf = 0; mf < 8; mf++)
#pragma unroll
      for (int j = 0; j < 4; j++) {
        int slot = m0 + wv * 128 + mf * 16 + koff + j;
        if (slot < cnt_e) {
#pragma unroll
          for (int f = 0; f < 2; f++) {
            int col = n0 + f * 16 + (lane & 15);
            float g = acc0[mf][f][j], u = acc1[mf][f][j];
            float val = g / (1.f + expf(-g)) * u;
            *(f16*)(Hb + (size_t)(col >> 5) * 32768 + slot * 64 + (col & 31) * 2) = (f16)val;
          }
        }
      }
  } else {
    float* Of = (float*)outp;
    const int* tokp = tokL + e * CAP;
    const float* wtp = wtL + e * CAP;
#pragma unroll
    for (int mf = 0; mf < 8; mf++)
#pragma unroll
      for (int j = 0; j < 4; j++) {
        int slot = m0 + wv * 128 + mf * 16 + koff + j;
        if (slot < cnt_e) {
          int tk = tokp[slot];
          float w = wtp[slot];
#pragma unroll
          for (int f = 0; f < 2; f++) {
            int col = n0 + f * 16 + (lane & 15);
            atomicAdd(Of + (size_t)tk * HDIM + col, acc0[mf][f][j] * w);
            atomicAdd(Of + (size_t)tk * HDIM + col + 32, acc1[mf][f][j] * w);
          }
        }
      }
  }
}

// ---------------- shared GEMM (R9 4-wave depth-4 template, modes 1/3 only) ----------------
// MODE 1: shared up (dual sg/su, A=xbt, -> hs k-chunked)
// MODE 3: shared down (sd, A=hs, plain store out)
template<int MODE>
__global__ __launch_bounds__(256, 2)
void gemm_kernel(const f16* __restrict__ Ag, const float* __restrict__ B0g,
                 const float* __restrict__ B1g, void* __restrict__ outp) {
  constexpr bool DUAL = (MODE == 1);
  constexpr bool SINGLE = (MODE == 3);
  constexpr int MF = 4;
  constexpr int WM = 64;
  constexpr int KD = 2048;
  constexpr int NK = KD / 32;
  constexpr int ND = 2048;
  constexpr size_t TS = 131072;
  constexpr int LDSB = (SINGLE ? 1 : 2) * 2048;

  int bid = blockIdx.x;
  int tid = threadIdx.x, lane = tid & 63, wv = tid >> 6;

  int mstart = (bid & 7) * 256;
  int n0 = (bid >> 3) * 32;

  const char* Ab = (const char*)Ag;
  const float* B0 = B0g;
  const float* B1 = B1g;

  __shared__ __align__(16) char lds[2 * LDSB];

  int kb = tid >> 3;
  int nb4 = (tid & 7) * 4;
  const float* Bk0 = B0 + (size_t)kb * ND + n0 + nb4;
  const float* Bk1 = DUAL ? (B1 + (size_t)kb * ND + n0 + nb4) : nullptr;

  f32x4 sA0, sA1, sB0, sB1, sC0, sC1, sD0, sD1;
  half8 af[MF];
  half8 bf0[2];
  half8 bf1[SINGLE ? 1 : 2];

#define LOADB(tt, X0, X1) { \
    const float* _p = Bk0 + (size_t)(tt) * (32 * ND); \
    X0 = *(const f32x4*)_p; \
    if constexpr (DUAL) X1 = *(const f32x4*)(Bk1 + (size_t)(tt) * (32 * ND)); }

#define WRITEB(X0, X1, par) { \
    char* _b = lds + (par) * LDSB; \
    _Pragma("unroll") \
    for (int _q = 0; _q < 4; _q++) { \
      int _n = nb4 + _q; \
      int _off = _n * 64 + (((kb >> 3) ^ swz3(_n)) << 4) + (kb & 7) * 2; \
      *(f16*)(_b + _off) = (f16)X0[_q]; \
      if constexpr (!SINGLE) *(f16*)(_b + 2048 + _off) = (f16)X1[_q]; \
    } }

#define BFREAD(par) { \
    _Pragma("unroll") \
    for (int _f = 0; _f < 2; _f++) { \
      int _n = _f * 16 + (lane & 15); \
      int _off = (par) * LDSB + _n * 64 + (((lane >> 4) ^ swz3(_n)) << 4); \
      bf0[_f] = *(const half8*)(lds + _off); \
      if constexpr (!SINGLE) bf1[_f] = *(const half8*)(lds + 2048 + _off); \
    } }

#define LOADA(tt) { \
    _Pragma("unroll") \
    for (int _m = 0; _m < MF; _m++) \
      af[_m] = *(const half8*)(Ab + (size_t)(tt) * TS + aoff[_m]); }

#define DOMFMA() { \
    _Pragma("unroll") \
    for (int _m = 0; _m < MF; _m++) { \
      _Pragma("unroll") \
      for (int _f = 0; _f < 2; _f++) { \
        acc0[_m][_f] = __builtin_amdgcn_mfma_f32_16x16x32_f16(af[_m], bf0[_f], acc0[_m][_f], 0, 0, 0); \
        if constexpr (!SINGLE) \
          acc1[_m][_f] = __builtin_amdgcn_mfma_f32_16x16x32_f16(af[_m], bf1[_f], acc1[_m][_f], 0, 0, 0); \
      } } }

#define SYNC() { asm volatile("s_waitcnt lgkmcnt(0)" ::: "memory"); __builtin_amdgcn_s_barrier(); }

  int m0 = mstart;
  unsigned aoff[MF];
#pragma unroll
  for (int mf = 0; mf < MF; mf++) {
    int row = m0 + wv * WM + mf * 16 + (lane & 15);
    aoff[mf] = row * 64 + ((lane >> 4) << 4);
  }

  f32x4 acc0[MF][2];
  f32x4 acc1[SINGLE ? 1 : MF][SINGLE ? 1 : 2];
#pragma unroll
  for (int mf = 0; mf < MF; mf++)
#pragma unroll
    for (int f = 0; f < 2; f++) acc0[mf][f] = (f32x4){0.f, 0.f, 0.f, 0.f};
  if constexpr (!SINGLE) {
#pragma unroll
    for (int mf = 0; mf < MF; mf++)
#pragma unroll
      for (int f = 0; f < 2; f++) acc1[mf][f] = (f32x4){0.f, 0.f, 0.f, 0.f};
  }

  LOADB(0, sA0, sA1)
  LOADB(1, sB0, sB1)
  LOADB(2, sC0, sC1)
  LOADB(3, sD0, sD1)
  WRITEB(sA0, sA1, 0)
  LOADA(0)
  SYNC()

  for (int u = 0; u < NK; u += 4) {
    BFREAD(0)
    WRITEB(sB0, sB1, 1)
    if (u + 4 < NK) LOADB(u + 4, sA0, sA1)
    DOMFMA()
    LOADA(u + 1)
    SYNC()
    BFREAD(1)
    WRITEB(sC0, sC1, 0)
    if (u + 5 < NK) LOADB(u + 5, sB0, sB1)
    DOMFMA()
    LOADA(u + 2)
    SYNC()
    BFREAD(0)
    WRITEB(sD0, sD1, 1)
    if (u + 6 < NK) LOADB(u + 6, sC0, sC1)
    DOMFMA()
    LOADA(u + 3)
    SYNC()
    BFREAD(1)
    if (u + 4 < NK) WRITEB(sA0, sA1, 0)
    if (u + 7 < NK) LOADB(u + 7, sD0, sD1)
    DOMFMA()
    if (u + 4 < NK) {
      LOADA(u + 4)
      SYNC()
    }
  }

#undef LOADB
#undef WRITEB
#undef BFREAD
#undef LOADA
#undef DOMFMA
#undef SYNC

  int koff = (lane >> 4) << 2;
  if constexpr (MODE == 1) {
    char* Hb = (char*)outp;
#pragma unroll
    for (int mf = 0; mf < MF; mf++)
#pragma unroll
      for (int j = 0; j < 4; j++) {
        int row = m0 + wv * WM + mf * 16 + koff + j;
#pragma unroll
        for (int f = 0; f < 2; f++) {
          int col = n0 + f * 16 + (lane & 15);
          float g = acc0[mf][f][j], u = acc1[mf][f][j];
          float val = g / (1.f + expf(-g)) * u;
          *(f16*)(Hb + (size_t)(col >> 5) * 131072 + row * 64 + (col & 31) * 2) = (f16)val;
        }
      }
  } else {
    float* Of = (float*)outp;
#pragma unroll
    for (int mf = 0; mf < MF; mf++)
#pragma unroll
      for (int j = 0; j < 4; j++) {
        int row = m0 + wv * WM + mf * 16 + koff + j;
#pragma unroll
        for (int f = 0; f < 2; f++) {
          int col = n0 + f * 16 + (lane & 15);
          Of[(size_t)row * HDIM + col] = acc0[mf][f][j];
        }
      }
  }
}

// ---------------- launch ----------------
extern "C" void kernel_launch(void* const* d_in, const int* in_sizes, int n_in,
                              void* d_out, int out_size, void* d_ws, size_t ws_size,
                              hipStream_t stream) {
  const float* x  = (const float*)d_in[0];
  const float* gw = (const float*)d_in[1];
  const float* gb = (const float*)d_in[2];
  const float* w1 = (const float*)d_in[3];
  const float* w2 = (const float*)d_in[4];
  const float* w3 = (const float*)d_in[5];
  const float* sg = (const float*)d_in[6];
  const float* su = (const float*)d_in[7];
  const float* sd = (const float*)d_in[8];
  float* out = (float*)d_out;
  char* ws = (char*)d_ws;

  f16*   xbt = (f16*)(ws);                 // 8 MB  k-chunked x fp16
  f16*   hs  = (f16*)(ws + 8388608);       // 8 MB  k-chunked shared-mid
  f16*   hbuf= (f16*)(ws + 16777216);      // 32 MB k-chunked routed-mid
  f16*   xg  = (f16*)(ws + 50331648);      // 64 MB compact gathered A
  int*   tok = (int*)(ws + 117440512);
  float* wt  = (float*)(ws + 117506048);
  int*   tidx= (int*)(ws + 117571584);
  float* tw  = (float*)(ws + 117604352);
  int*   cnt = (int*)(ws + 117637120);

  gateconv_kernel<<<2048, 256, 0, stream>>>(x, gw, gb, tidx, tw, xbt);
  dispatch_kernel<<<32, 256, 0, stream>>>(tidx, tw, tok, wt, cnt);
  gather_kernel<<<2048, 256, 0, stream>>>(xbt, tok, cnt, xg);

  // routed up: hbuf = silu(Xg@w1)*(Xg@w3)   grid = 32e x 2m x 32n, 128-thread blocks
  gemm2_kernel<0><<<2048, 128, 0, stream>>>(xg, w1, w3, hbuf, tok, wt, cnt);
  // shared up: hs = silu(x@sg)*(x@su)       grid = 8m x 64n
  gemm_kernel<1><<<512, 256, 0, stream>>>(xbt, sg, su, hs);
  // shared down: out = hs @ sd              grid = 8m x 64n
  gemm_kernel<3><<<512, 256, 0, stream>>>(hs, sd, nullptr, out);
  // routed down: out += w * (hbuf @ w2)     grid = 32e x 2m x 32n
  gemm2_kernel<2><<<2048, 128, 0, stream>>>(hbuf, w2, nullptr, out, tok, wt, cnt);
}

// Round 11
// 545.355 us; speedup vs baseline: 2.6145x; 1.0974x over previous
//
#include <hip/hip_runtime.h>
#include <stdint.h>
#include <math.h>

#define NTOK 2048
#define HDIM 2048
#define FDIM 1024
#define NEXP 32
#define TOPK 4
#define NGRP 4
#define CAP  512

typedef _Float16 f16;
typedef _Float16 half8 __attribute__((ext_vector_type(8)));
typedef float f32x4 __attribute__((ext_vector_type(4)));

__device__ __forceinline__ int swz3(int n) { return (n ^ (n >> 2)) & 3; }

// ---------------- fused gate + convert (x row -> logits AND k-chunked fp16) ----------------
__global__ __launch_bounds__(256) void gateconv_kernel(const float* __restrict__ x,
                                                       const float* __restrict__ gw,
                                                       const float* __restrict__ gb,
                                                       int* __restrict__ tidx,
                                                       float* __restrict__ tw,
                                                       f16* __restrict__ xbt) {
  int t = blockIdx.x;
  int tid = threadIdx.x;
  int e = tid >> 3, p = tid & 7;
  const f32x4* xr = (const f32x4*)(x + (size_t)t * HDIM);
  const f32x4* wr = (const f32x4*)(gw + (size_t)e * HDIM);
  float s = 0.f;
  for (int c = 0; c < 64; c++) {
    f32x4 a = xr[p + c * 8], w = wr[p + c * 8];
    s += a[0] * w[0] + a[1] * w[1] + a[2] * w[2] + a[3] * w[3];
  }
  s += __shfl_down(s, 4, 8);
  s += __shfl_down(s, 2, 8);
  s += __shfl_down(s, 1, 8);
  __shared__ float lg[NEXP];
  if (p == 0) lg[e] = s;

  {
    int c8 = tid * 8;
    const float* pp = x + (size_t)t * HDIM + c8;
    f32x4 a = *(const f32x4*)pp;
    f32x4 b = *(const f32x4*)(pp + 4);
    half8 v;
    v[0] = (f16)a[0]; v[1] = (f16)a[1]; v[2] = (f16)a[2]; v[3] = (f16)a[3];
    v[4] = (f16)b[0]; v[5] = (f16)b[1]; v[6] = (f16)b[2]; v[7] = (f16)b[3];
    *(half8*)((char*)xbt + (size_t)(c8 >> 5) * 131072 + t * 64 + (c8 & 31) * 2) = v;
  }

  __syncthreads();
  if (tid == 0) {
    float sc[NEXP], scb[NEXP];
    for (int i = 0; i < NEXP; i++) {
      sc[i] = 1.f / (1.f + expf(-lg[i]));
      scb[i] = sc[i] + gb[i];
    }
    float gs[NGRP];
    for (int g = 0; g < NGRP; g++) {
      float m1 = -1e30f, m2 = -1e30f;
      for (int j = 0; j < 8; j++) {
        float v = scb[g * 8 + j];
        if (v > m1) { m2 = m1; m1 = v; }
        else if (v > m2) m2 = v;
      }
      gs[g] = m1 + m2;
    }
    int g1 = 0; float bv = gs[0];
    for (int g = 1; g < NGRP; g++) if (gs[g] > bv) { bv = gs[g]; g1 = g; }
    int g2 = -1; bv = -1e30f;
    for (int g = 0; g < NGRP; g++) if (g != g1 && gs[g] > bv) { bv = gs[g]; g2 = g; }
    float cand[NEXP];
    for (int i = 0; i < NEXP; i++) {
      int g = i >> 3;
      cand[i] = (g == g1 || g == g2) ? scb[i] : 0.0f;
    }
    int isel[TOPK]; float wsel[TOPK]; float wsum = 0.f;
    bool used[NEXP] = {};
    for (int k = 0; k < TOPK; k++) {
      int best = 0; float bw = -1e30f;
      for (int i = 0; i < NEXP; i++)
        if (!used[i] && cand[i] > bw) { bw = cand[i]; best = i; }
      used[best] = true;
      isel[k] = best;
      wsel[k] = sc[best];
      wsum += wsel[k];
    }
    float inv = 2.0f / (wsum + 1e-20f);
    for (int k = 0; k < TOPK; k++) {
      tidx[t * TOPK + k] = isel[k];
      tw[t * TOPK + k] = wsel[k] * inv;
    }
  }
}

// ---------------- dispatch ----------------
__global__ __launch_bounds__(256) void dispatch_kernel(const int* __restrict__ tidx,
                                                       const float* __restrict__ tw,
                                                       int* __restrict__ tok,
                                                       float* __restrict__ wt,
                                                       int* __restrict__ cnt) {
  int e = blockIdx.x, tid = threadIdx.x, wv = tid >> 6, lane = tid & 63;
  __shared__ int wsum[4];
  __shared__ int sbase;
  if (tid == 0) sbase = 0;
  __syncthreads();
  for (int c = 0; c < (NTOK * TOPK) / 256; c++) {
    int i = c * 256 + tid;
    int fe = tidx[i];
    bool flag = (fe == e);
    unsigned long long b = __ballot(flag ? 1 : 0);
    int lr = __popcll(b & ((1ull << lane) - 1ull));
    if (lane == 0) wsum[wv] = __popcll(b);
    __syncthreads();
    int off = 0;
    for (int w2 = 0; w2 < wv; w2++) off += wsum[w2];
    int tot = wsum[0] + wsum[1] + wsum[2] + wsum[3];
    int base = sbase;
    if (flag) {
      int pos = base + off + lr;
      if (pos < CAP) {
        tok[e * CAP + pos] = i >> 2;
        wt[e * CAP + pos] = tw[i];
      }
    }
    __syncthreads();
    if (tid == 0) sbase = base + tot;
  }
  __syncthreads();
  if (tid == 0) cnt[e] = min(sbase, CAP);
}

// ---------------- gather: xg[e][kt][slot][32k] = xbt[kt][tok[e][slot]] ----------------
__global__ __launch_bounds__(256) void gather_kernel(const f16* __restrict__ xbt,
                                                     const int* __restrict__ tok,
                                                     const int* __restrict__ cnt,
                                                     f16* __restrict__ xg) {
  int bid = blockIdx.x;
  int t = bid & 63, e = bid >> 6;
  int cn = cnt[e];
  int tid = threadIdx.x;
  char* dst = (char*)xg + (size_t)e * 2097152 + (size_t)t * 32768;
  const char* srcb = (const char*)xbt + (size_t)t * 131072;
  for (int s = tid; s < cn; s += 256) {
    const uint4* sp = (const uint4*)(srcb + (size_t)tok[e * CAP + s] * 64);
    uint4 v0 = sp[0], v1 = sp[1], v2 = sp[2], v3 = sp[3];
    uint4* dp = (uint4*)(dst + s * 64);
    dp[0] = v0; dp[1] = v1; dp[2] = v2; dp[3] = v3;
  }
}

// ---------------- R6 GEMM body (barrier-decoupled): A global->VGPR frags, B reg->LDS dbuf ----------------
// MODE 0: routed up (dual w1/w3, A=xg[e], silu-mul -> hbuf k-chunked)
// MODE 1: shared up (dual sg/su, A=xbt, -> hs k-chunked)
// MODE 2: routed down (w2, 64-wide, A=hbuf[e], atomicAdd out)
// MODE 3: shared down (sd, A=hs, atomicAdd out [fused with mode2; out pre-zeroed])
template<int MODE>
__device__ void gemm_body(int bid, const f16* __restrict__ Ag, const float* __restrict__ B0g,
                          const float* __restrict__ B1g, void* __restrict__ outp,
                          const int* __restrict__ tokL, const float* __restrict__ wtL,
                          const int* __restrict__ cntP, char* bs) {
  constexpr int BM = (MODE == 0 || MODE == 2) ? 512 : 256;
  constexpr int BN = (MODE == 2) ? 64 : 32;
  constexpr bool DUAL = (MODE <= 1);
  constexpr int MF = BM / 64;
  constexpr int NF = BN / 16;
  constexpr int KD = (MODE == 2) ? 1024 : 2048;
  constexpr int NK = KD / 32;
  constexpr int ND = (MODE == 0) ? 1024 : 2048;
  constexpr size_t TS = (MODE == 0 || MODE == 2) ? 32768 : 131072;  // A k-chunk byte stride
  constexpr int BSZ = (DUAL ? 2 : 1) * BN * 64;

  int tid = threadIdx.x, lane = tid & 63, wv = tid >> 6;
  int e = 0, m0 = 0, n0 = 0;
  if constexpr (MODE == 0 || MODE == 2) {
    e = (bid & 7) + ((bid >> 3) >> 5) * 8;   // XCD-clustered experts
    n0 = ((bid >> 3) & 31) * BN;
  } else {
    n0 = ((bid & 7) * 8 + ((bid >> 3) & 7)) * 32;
    m0 = ((bid >> 3) >> 3) * 256;
  }

  const char* Ab = (const char*)Ag;
  const float* B0 = B0g;
  const float* B1 = B1g;
  int Mcur = 0;
  if constexpr (MODE == 0 || MODE == 2) {
    Mcur = cntP[e];
    Ab += (size_t)e * ((MODE == 0) ? 2097152 : 1048576);
    B0 += (size_t)e * ((size_t)KD * ND);
    if constexpr (MODE == 0) B1 += (size_t)e * ((size_t)KD * ND);
  }

  int kb = tid >> 3;                 // B k-row 0..31
  int nbL = (tid & 7) * (BN / 8);    // B n base (4 or 8 cols per thread)

  unsigned voff[MF];
#pragma unroll
  for (int mf = 0; mf < MF; mf++) {
    int row = ((MODE == 0 || MODE == 2) ? (wv * (BM / 4)) : (m0 + wv * 64)) + mf * 16 + (lane & 15);
    voff[mf] = row * 64 + ((lane >> 4) << 4);
  }

  f32x4 acc0[MF][NF];
  f32x4 acc1[DUAL ? MF : 1][DUAL ? NF : 1];
#pragma unroll
  for (int mf = 0; mf < MF; mf++)
#pragma unroll
    for (int nf = 0; nf < NF; nf++) acc0[mf][nf] = (f32x4){0.f, 0.f, 0.f, 0.f};
  if constexpr (DUAL) {
#pragma unroll
    for (int mf = 0; mf < MF; mf++)
#pragma unroll
      for (int nf = 0; nf < NF; nf++) acc1[mf][nf] = (f32x4){0.f, 0.f, 0.f, 0.f};
  }

  half8 af[MF];
  half8 bf0[NF];
  half8 bf1[DUAL ? NF : 1];
  f32x4 bE0, bE1, bO0, bO1;

  auto loadB = [&](int t, f32x4& X, f32x4& Y) {
    const float* s = B0 + (size_t)(t * 32 + kb) * ND + n0 + nbL;
    X = *(const f32x4*)s;
    if constexpr (DUAL) {
      Y = *(const f32x4*)(B1 + (size_t)(t * 32 + kb) * ND + n0 + nbL);
    } else if constexpr (MODE == 2) {
      Y = *(const f32x4*)(s + 4);
    }
  };
  auto writeB = [&](const f32x4& X, const f32x4& Y, int par) {
    char* base = bs + par * BSZ;
#pragma unroll
    for (int q = 0; q < 4; q++) {
      int n = nbL + q;
      int off = n * 64 + (((kb >> 3) ^ swz3(n)) << 4) + (kb & 7) * 2;
      *(f16*)(base + off) = (f16)X[q];
      if constexpr (DUAL) {
        *(f16*)(base + BN * 64 + off) = (f16)Y[q];
      } else if constexpr (MODE == 2) {
        int n2 = n + 4;
        int off2 = n2 * 64 + (((kb >> 3) ^ swz3(n2)) << 4) + (kb & 7) * 2;
        *(f16*)(base + off2) = (f16)Y[q];
      }
    }
  };
  auto bfread = [&](int par) {
#pragma unroll
    for (int nf = 0; nf < NF; nf++) {
      int n = nf * 16 + (lane & 15);
      int off = par * BSZ + n * 64 + (((lane >> 4) ^ swz3(n)) << 4);
      bf0[nf] = *(const half8*)(bs + off);
      if constexpr (DUAL) bf1[nf] = *(const half8*)(bs + BN * 64 + off);
    }
  };
  auto loadAf = [&](int t) {
#pragma unroll
    for (int mf = 0; mf < MF; mf++)
      af[mf] = *(const half8*)(Ab + (size_t)t * TS + voff[mf]);
  };
  auto domfma = [&]() {
#pragma unroll
    for (int mf = 0; mf < MF; mf++)
#pragma unroll
      for (int nf = 0; nf < NF; nf++) {
        acc0[mf][nf] = __builtin_amdgcn_mfma_f32_16x16x32_f16(af[mf], bf0[nf], acc0[mf][nf], 0, 0, 0);
        if constexpr (DUAL)
          acc1[mf][nf] = __builtin_amdgcn_mfma_f32_16x16x32_f16(af[mf], bf1[nf], acc1[mf][nf], 0, 0, 0);
      }
  };

  // Prologue
  loadB(0, bE0, bE1);
  loadB(1, bO0, bO1);
  loadAf(0);
  writeB(bE0, bE1, 0);
  asm volatile("s_waitcnt lgkmcnt(0)" ::: "memory");
  __builtin_amdgcn_s_barrier();

  for (int t = 0; t < NK; t += 2) {
    bfread(0);
    writeB(bO0, bO1, 1);
    if (t + 2 < NK) loadB(t + 2, bE0, bE1);
    domfma();
    loadAf(t + 1 < NK ? t + 1 : t);
    asm volatile("s_waitcnt lgkmcnt(0)" ::: "memory");
    __builtin_amdgcn_s_barrier();
    bfread(1);
    if (t + 2 < NK) writeB(bE0, bE1, 0);
    if (t + 3 < NK) loadB(t + 3, bO0, bO1);
    domfma();
    if (t + 2 < NK) {
      loadAf(t + 2);
      asm volatile("s_waitcnt lgkmcnt(0)" ::: "memory");
      __builtin_amdgcn_s_barrier();
    }
  }

  // epilogue
  int koff = (lane >> 4) << 2;
  if constexpr (MODE == 0) {
    char* Hb = (char*)outp + (size_t)e * 1048576;
#pragma unroll
    for (int mf = 0; mf < MF; mf++)
#pragma unroll
      for (int j = 0; j < 4; j++) {
        int slot = wv * 128 + mf * 16 + koff + j;
        if (slot < Mcur) {
#pragma unroll
          for (int nf = 0; nf < NF; nf++) {
            int col = n0 + nf * 16 + (lane & 15);
            float g = acc0[mf][nf][j], u = acc1[mf][nf][j];
            float val = g / (1.f + expf(-g)) * u;
            *(f16*)(Hb + (size_t)(col >> 5) * 32768 + slot * 64 + (col & 31) * 2) = (f16)val;
          }
        }
      }
  } else if constexpr (MODE == 1) {
    char* Hb = (char*)outp;
#pragma unroll
    for (int mf = 0; mf < MF; mf++)
#pragma unroll
      for (int j = 0; j < 4; j++) {
        int row = m0 + wv * 64 + mf * 16 + koff + j;
#pragma unroll
        for (int nf = 0; nf < NF; nf++) {
          int col = n0 + nf * 16 + (lane & 15);
          float g = acc0[mf][nf][j], u = acc1[mf][nf][j];
          float val = g / (1.f + expf(-g)) * u;
          *(f16*)(Hb + (size_t)(col >> 5) * 131072 + row * 64 + (col & 31) * 2) = (f16)val;
        }
      }
  } else if constexpr (MODE == 2) {
    float* Of = (float*)outp;
    const int* tokp = tokL + e * CAP;
    const float* wtp = wtL + e * CAP;
#pragma unroll
    for (int mf = 0; mf < MF; mf++)
#pragma unroll
      for (int j = 0; j < 4; j++) {
        int slot = wv * 128 + mf * 16 + koff + j;
        if (slot < Mcur) {
          int tk = tokp[slot];
          float w = wtp[slot];
#pragma unroll
          for (int nf = 0; nf < NF; nf++) {
            int col = n0 + nf * 16 + (lane & 15);
            atomicAdd(Of + (size_t)tk * HDIM + col, acc0[mf][nf][j] * w);
          }
        }
      }
  } else {
    float* Of = (float*)outp;
#pragma unroll
    for (int mf = 0; mf < MF; mf++)
#pragma unroll
      for (int j = 0; j < 4; j++) {
        int row = m0 + wv * 64 + mf * 16 + koff + j;
#pragma unroll
        for (int nf = 0; nf < NF; nf++) {
          int col = n0 + nf * 16 + (lane & 15);
          atomicAdd(Of + (size_t)row * HDIM + col, acc0[mf][nf][j]);
        }
      }
  }
}

// ---------------- fused dispatches: {mode0 | mode1} and {mode2 | mode3} ----------------
__global__ __launch_bounds__(256, 2) void fused_up_kernel(
    const f16* __restrict__ xg, const f16* __restrict__ xbt,
    const float* __restrict__ w1, const float* __restrict__ w3,
    const float* __restrict__ sg, const float* __restrict__ su,
    void* __restrict__ hbuf, void* __restrict__ hs, const int* __restrict__ cnt) {
  __shared__ __align__(16) char bs[8192];
  int bid = blockIdx.x;
  if (bid < 1024) gemm_body<0>(bid, xg, w1, w3, hbuf, nullptr, nullptr, cnt, bs);
  else            gemm_body<1>(bid - 1024, xbt, sg, su, hs, nullptr, nullptr, nullptr, bs);
}

__global__ __launch_bounds__(256, 2) void fused_down_kernel(
    const f16* __restrict__ hbuf, const f16* __restrict__ hs,
    const float* __restrict__ w2, const float* __restrict__ sd,
    float* __restrict__ out, const int* __restrict__ tok,
    const float* __restrict__ wt, const int* __restrict__ cnt) {
  __shared__ __align__(16) char bs[8192];
  int bid = blockIdx.x;
  if (bid < 1024) gemm_body<2>(bid, hbuf, w2, nullptr, out, tok, wt, cnt, bs);
  else            gemm_body<3>(bid - 1024, hs, sd, nullptr, out, nullptr, nullptr, nullptr, bs);
}

// ---------------- launch ----------------
extern "C" void kernel_launch(void* const* d_in, const int* in_sizes, int n_in,
                              void* d_out, int out_size, void* d_ws, size_t ws_size,
                              hipStream_t stream) {
  const float* x  = (const float*)d_in[0];
  const float* gw = (const float*)d_in[1];
  const float* gb = (const float*)d_in[2];
  const float* w1 = (const float*)d_in[3];
  const float* w2 = (const float*)d_in[4];
  const float* w3 = (const float*)d_in[5];
  const float* sg = (const float*)d_in[6];
  const float* su = (const float*)d_in[7];
  const float* sd = (const float*)d_in[8];
  float* out = (float*)d_out;
  char* ws = (char*)d_ws;

  f16*   xbt = (f16*)(ws);                 // 8 MB  k-chunked x fp16
  f16*   hs  = (f16*)(ws + 8388608);       // 8 MB  k-chunked shared-mid
  f16*   hbuf= (f16*)(ws + 16777216);      // 32 MB k-chunked routed-mid
  f16*   xg  = (f16*)(ws + 50331648);      // 64 MB compact gathered A
  int*   tok = (int*)(ws + 117440512);
  float* wt  = (float*)(ws + 117506048);
  int*   tidx= (int*)(ws + 117571584);
  float* tw  = (float*)(ws + 117604352);
  int*   cnt = (int*)(ws + 117637120);

  gateconv_kernel<<<2048, 256, 0, stream>>>(x, gw, gb, tidx, tw, xbt);
  dispatch_kernel<<<32, 256, 0, stream>>>(tidx, tw, tok, wt, cnt);
  gather_kernel<<<2048, 256, 0, stream>>>(xbt, tok, cnt, xg);

  // phase 1: routed-up (1024 blk) || shared-up (512 blk)
  fused_up_kernel<<<1536, 256, 0, stream>>>(xg, xbt, w1, w3, sg, su, hbuf, hs, cnt);

  // out = 0, then phase 2: routed-down atomics (1024 blk) || shared-down atomics (512 blk)
  hipMemsetAsync(out, 0, (size_t)out_size * sizeof(float), stream);
  fused_down_kernel<<<1536, 256, 0, stream>>>(hbuf, hs, w2, sd, out, tok, wt, cnt);
}